// Round 4
// baseline (318.323 us; speedup 1.0000x reference)
//
#include <hip/hip_runtime.h>

#define NTOK 4096
#define DDIM 1024
#define IDIM 704
#define NEXP 16
#define NSLOT 8192
#define MAXT 128
#define RTRBLK 512   // router blocks: 8 tokens each

typedef __attribute__((ext_vector_type(8))) short bf16x8;
typedef __attribute__((ext_vector_type(4))) float f32x4;
typedef __attribute__((ext_vector_type(4))) unsigned short us4;
typedef __attribute__((ext_vector_type(2))) unsigned int u32x2;

__device__ __forceinline__ unsigned short f2bf(float f) {
  union { float f; unsigned int u; } v; v.f = f;
  unsigned int r = v.u + 0x7fffu + ((v.u >> 16) & 1u);
  return (unsigned short)(r >> 16);
}

__device__ __forceinline__ float bf2f(unsigned short b) {
  union { unsigned int u; float f; } v; v.u = ((unsigned int)b) << 16;
  return v.f;
}

__device__ __forceinline__ unsigned int cvt_pk_bf16(float a, float b) {
  unsigned int r;
  asm("v_cvt_pk_bf16_f32 %0, %1, %2" : "=v"(r) : "v"(a), "v"(b));
  return r;   // [15:0]=bf16(a), [31:16]=bf16(b)  (RNE)
}

__device__ __forceinline__ void gload_lds16(const void* g, void* l) {
  __builtin_amdgcn_global_load_lds((const __attribute__((address_space(1))) void*)g,
                                   (__attribute__((address_space(3))) void*)l, 16, 0, 0);
}

// ---- fused B staging helpers: fp32 [k][n] panel -> LDS bf16 [128 n][32 k] ----
// thread t: kk = t>>5 (k-quad of 4 rows), nq = t&31 (n-quad of 4 cols).
// Global: 4 x f32x4, 32 consecutive lanes cover one 512B k-row segment.
// LDS: row = nq*4+c, k-octet chunk q16 at phys = q16 ^ ((row>>2)&3) = q16 ^ (nq&3).
__device__ __forceinline__ void load_b(const float* wt, int ns, bool ok, f32x4* v) {
#pragma unroll
  for (int j = 0; j < 4; ++j)
    v[j] = ok ? *(const f32x4*)(wt + (size_t)j * ns) : (f32x4)0.f;
}

__device__ __forceinline__ void write_b(const f32x4* v, unsigned short* buf, int kk, int nq) {
  int h8 = (kk & 1) * 8;
  int phys = (kk >> 1) ^ (nq & 3);
#pragma unroll
  for (int c = 0; c < 4; ++c) {
    int row = nq * 4 + c;
    u32x2 o = { cvt_pk_bf16(v[0][c], v[1][c]), cvt_pk_bf16(v[2][c], v[3][c]) };
    *(u32x2*)((char*)buf + row * 64 + phys * 16 + h8) = o;
  }
}

// ---------------- front: router only (transpose eliminated — fused into GEMMs) ----
__global__ __launch_bounds__(256, 4)
void k_front(const float* __restrict__ x, const float* __restrict__ Wg,
             int* __restrict__ tok_e, float* __restrict__ tok_w,
             unsigned short* __restrict__ Xb) {
  int b = blockIdx.x;
  int lane = threadIdx.x & 63;
  int wv = threadIdx.x >> 6;
  int tk0 = b * 8 + wv * 2;
  f32x4 xv[2][4];
#pragma unroll
  for (int tok = 0; tok < 2; ++tok) {
    const f32x4* xr = (const f32x4*)(x + (size_t)(tk0 + tok) * DDIM);
    us4* xbr = (us4*)(Xb + (size_t)(tk0 + tok) * DDIM);
#pragma unroll
    for (int c = 0; c < 4; ++c) {
      xv[tok][c] = xr[c * 64 + lane];
      us4 o;
#pragma unroll
      for (int j = 0; j < 4; ++j) o[j] = f2bf(xv[tok][c][j]);
      xbr[c * 64 + lane] = o;
    }
  }
  float p[2][NEXP];
#pragma unroll
  for (int e = 0; e < NEXP; ++e) {
    const f32x4* wr = (const f32x4*)(Wg + (size_t)e * DDIM);
    float s0 = 0.f, s1 = 0.f;
#pragma unroll
    for (int c = 0; c < 4; ++c) {
      f32x4 w4 = wr[c * 64 + lane];
      s0 += xv[0][c][0]*w4[0] + xv[0][c][1]*w4[1] + xv[0][c][2]*w4[2] + xv[0][c][3]*w4[3];
      s1 += xv[1][c][0]*w4[0] + xv[1][c][1]*w4[1] + xv[1][c][2]*w4[2] + xv[1][c][3]*w4[3];
    }
    p[0][e] = s0; p[1][e] = s1;
  }
#pragma unroll
  for (int off = 32; off >= 1; off >>= 1)
#pragma unroll
    for (int e = 0; e < NEXP; ++e) {
      p[0][e] += __shfl_xor(p[0][e], off);
      p[1][e] += __shfl_xor(p[1][e], off);
    }
#pragma unroll
  for (int tok = 0; tok < 2; ++tok) {
    int i0 = 0; float b0 = p[tok][0];
#pragma unroll
    for (int e = 1; e < NEXP; ++e) if (p[tok][e] > b0) { b0 = p[tok][e]; i0 = e; }
    int i1 = -1; float b1 = -3.4e38f;
#pragma unroll
    for (int e = 0; e < NEXP; ++e) if (e != i0 && p[tok][e] > b1) { b1 = p[tok][e]; i1 = e; }
    if (lane == 0) {
      int tk = tk0 + tok;
      float w0 = 1.f / (1.f + __expf(b1 - b0));   // renormalized top-2 softmax weight
      tok_e[2*tk] = i0; tok_e[2*tk+1] = i1;
      tok_w[2*tk] = w0; tok_w[2*tk+1] = 1.f - w0;
    }
  }
}

// ---------------- count+scan+scatter: 16 blocks, no atomics ----------------
__global__ void k_scan_scatter(const int* __restrict__ tok_e, const float* __restrict__ tok_w,
                               int* __restrict__ counts, int* __restrict__ offsets,
                               int* __restrict__ ntiles, int* __restrict__ tile_e,
                               int* __restrict__ tile_m0, int* __restrict__ token_map,
                               float* __restrict__ gate_w, int* __restrict__ slot_of) {
  int eb = blockIdx.x;
  int t = threadIdx.x, lane = t & 63, wv = t >> 6;
  __shared__ unsigned long long masks[4][32];   // expert-eb ballot per [wave][seg]
  __shared__ int wcnt[4][NEXP];                 // per-wave per-expert counts
  __shared__ int counts_s[NEXP];
  int ce[NEXP];
#pragma unroll
  for (int e = 0; e < NEXP; ++e) ce[e] = 0;
  int base = wv * 2048 + lane;
  int te = tok_e[base];
#pragma unroll 1
  for (int s = 0; s < 32; ++s) {
    int ten = (s < 31) ? tok_e[base + (s + 1) * 64] : 0;
    unsigned long long B0 = __ballot(te & 1);
    unsigned long long B1 = __ballot(te & 2);
    unsigned long long B2 = __ballot(te & 4);
    unsigned long long B3 = __ballot(te & 8);
#pragma unroll
    for (int e = 0; e < NEXP; ++e) {
      unsigned long long m = ((e & 1) ? B0 : ~B0) & ((e & 2) ? B1 : ~B1) &
                             ((e & 4) ? B2 : ~B2) & ((e & 8) ? B3 : ~B3);
      ce[e] += (int)__popcll(m);
      if (e == eb && lane == 0) masks[wv][s] = m;
    }
    te = ten;
  }
  if (lane == 0) {
#pragma unroll
    for (int e = 0; e < NEXP; ++e) wcnt[wv][e] = ce[e];
  }
  __syncthreads();
  if (t < NEXP) {
    int s = wcnt[0][t] + wcnt[1][t] + wcnt[2][t] + wcnt[3][t];
    counts_s[t] = s;
    if (eb == 0) counts[t] = s;
  }
  __syncthreads();
  if (eb == 0 && t == 0) {
    int acc = 0, nt = 0;
    for (int e = 0; e < NEXP; ++e) {
      offsets[e] = acc;
      int cc = counts_s[e];
      for (int m0 = 0; m0 < cc; m0 += 128) { tile_e[nt] = e; tile_m0[nt] = m0; ++nt; }
      acc += cc;
    }
    offsets[NEXP] = acc;
    *ntiles = nt;
  }
  int run = 0;
  for (int e = 0; e < eb; ++e) run += counts_s[e];            // expert base
  for (int w = 0; w < wv; ++w) run += wcnt[w][eb];            // wave base
  unsigned long long below = (lane == 63) ? 0x7fffffffffffffffull : ((1ull << lane) - 1ull);
#pragma unroll 1
  for (int s = 0; s < 32; ++s) {
    unsigned long long m = masks[wv][s];
    if ((m >> lane) & 1ull) {
      int i = wv * 2048 + s * 64 + lane;
      int slot = run + (int)__popcll(m & below);
      token_map[slot] = i >> 1;
      gate_w[slot] = tok_w[i];
      slot_of[i] = slot;
    }
    run += (int)__popcll(m);
  }
}

// ---------------- GEMM1: 128x128, fused fp32->bf16 B staging, XCD-swizzled ----------------
__global__ __launch_bounds__(256, 2)
void k_gemm1(const unsigned short* __restrict__ Xb, const float* __restrict__ W1,
             const float* __restrict__ W3, const int* __restrict__ token_map,
             const float* __restrict__ gate_w, const int* __restrict__ ntiles,
             const int* __restrict__ tile_e, const int* __restrict__ tile_m0,
             const int* __restrict__ offsets, const int* __restrict__ counts,
             unsigned short* __restrict__ H) {
  int idx = blockIdx.x;
  int xcd = idx & 7, r = idx >> 3;
  int g = (r >> 2) * 8 + xcd;       // 0..119
  int mm = r & 3;
  int ty = (g / 6) * 4 + mm;        // 0..79
  if (ty >= *ntiles) return;
  int n0 = (g % 6) * 128;
  int e = tile_e[ty], m0 = tile_m0[ty];
  int base_slot = offsets[e] + m0;
  int cnt = counts[e] - m0; if (cnt > 128) cnt = 128;

  __shared__ unsigned short As[2][128 * 32];
  __shared__ unsigned short B1s[2][128 * 32];
  __shared__ unsigned short B3s[2][128 * 32];

  int t = threadIdx.x;
  int arow = t >> 2, kc = (t & 3) * 8;
  int r0i = base_slot + arow;      if (r0i > NSLOT - 1) r0i = NSLOT - 1;
  int r1i = base_slot + 64 + arow; if (r1i > NSLOT - 1) r1i = NSLOT - 1;
  const unsigned short* ag0 = Xb + (size_t)token_map[r0i] * DDIM + kc;
  const unsigned short* ag1 = Xb + (size_t)token_map[r1i] * DDIM + kc;
  int d0 = t * 8, d1 = 2048 + t * 8;

  int kk = t >> 5, nq = t & 31;
  bool bok = (n0 + nq * 4 + 4) <= IDIM;   // zero-pad n>=704 (n0=640 block)
  const float* w1t = W1 + (size_t)e * DDIM * IDIM + (size_t)(kk * 4) * IDIM + (n0 + nq * 4);
  const float* w3t = W3 + (size_t)e * DDIM * IDIM + (size_t)(kk * 4) * IDIM + (n0 + nq * 4);

  int lane = t & 63, wv = t >> 6;
  int wm = (wv >> 1) * 64, wn = (wv & 1) * 64;
  int lm = lane & 15, kg = lane >> 4;
  int ao[4], bo[4];
#pragma unroll
  for (int i = 0; i < 4; ++i) {
    ao[i] = (wm + i * 16 + lm) * 32 + kg * 8;          // elements (A linear)
    int brow = wn + i * 16 + lm;
    bo[i] = brow * 64 + ((kg ^ ((brow >> 2) & 3)) << 4);  // bytes (B swizzled)
  }

  f32x4 acc1[4][4], acc3[4][4];
#pragma unroll
  for (int i = 0; i < 4; ++i)
#pragma unroll
    for (int j = 0; j < 4; ++j) { acc1[i][j] = 0.f; acc3[i][j] = 0.f; }

  {  // prologue: stage k-step 0
    gload_lds16(ag0, As[0] + d0);
    gload_lds16(ag1, As[0] + d1);
    f32x4 b1r[4], b3r[4];
    load_b(w1t, IDIM, bok, b1r);
    load_b(w3t, IDIM, bok, b3r);
    write_b(b1r, B1s[0], kk, nq);
    write_b(b3r, B3s[0], kk, nq);
  }

  for (int k0 = 0; k0 < DDIM; k0 += 32) {
    int cur = (k0 >> 5) & 1, nx = cur ^ 1;
    __syncthreads();
    f32x4 b1r[4], b3r[4];
    bool more = (k0 + 32) < DDIM;
    if (more) {
      int kn = k0 + 32;
      gload_lds16(ag0 + kn, As[nx] + d0);
      gload_lds16(ag1 + kn, As[nx] + d1);
      load_b(w1t + (size_t)kn * IDIM, IDIM, bok, b1r);
      load_b(w3t + (size_t)kn * IDIM, IDIM, bok, b3r);
    }
    bf16x8 av[4], b1v[4], b3v[4];
#pragma unroll
    for (int i = 0; i < 4; ++i) {
      av[i]  = *(const bf16x8*)(As[cur] + ao[i]);
      b1v[i] = *(const bf16x8*)((const char*)B1s[cur] + bo[i]);
      b3v[i] = *(const bf16x8*)((const char*)B3s[cur] + bo[i]);
    }
#pragma unroll
    for (int mi = 0; mi < 4; ++mi)
#pragma unroll
      for (int ni = 0; ni < 4; ++ni) {
        acc1[mi][ni] = __builtin_amdgcn_mfma_f32_16x16x32_bf16(av[mi], b1v[ni], acc1[mi][ni], 0, 0, 0);
        acc3[mi][ni] = __builtin_amdgcn_mfma_f32_16x16x32_bf16(av[mi], b3v[ni], acc3[mi][ni], 0, 0, 0);
      }
    if (more) {
      write_b(b1r, B1s[nx], kk, nq);
      write_b(b3r, B3s[nx], kk, nq);
    }
  }

#pragma unroll
  for (int mi = 0; mi < 4; ++mi)
#pragma unroll
    for (int rr = 0; rr < 4; ++rr) {
      int orow = wm + mi * 16 + kg * 4 + rr;
      if (orow < cnt) {
        int slot = base_slot + orow;
        float gw = gate_w[slot];
        unsigned short* hrow = H + (size_t)slot * IDIM;
#pragma unroll
        for (int ni = 0; ni < 4; ++ni) {
          int nn = n0 + wn + ni * 16 + lm;
          if (nn < IDIM) {
            float v1 = acc1[mi][ni][rr];
            float v3 = acc3[mi][ni][rr];
            float hh = v1 / (1.f + __expf(-v1)) * v3 * gw;
            hrow[nn] = f2bf(hh);
          }
        }
      }
    }
}

// ---------------- GEMM2: 128x128, fused fp32->bf16 B staging ----------------
__global__ __launch_bounds__(256, 3)
void k_gemm2(const unsigned short* __restrict__ H, const float* __restrict__ W2,
             const int* __restrict__ ntiles, const int* __restrict__ tile_e,
             const int* __restrict__ tile_m0, const int* __restrict__ offsets,
             const int* __restrict__ counts, unsigned short* __restrict__ O2) {
  int idx = blockIdx.x;
  int xcd = idx & 7, r = idx >> 3;
  int g = (r >> 2) * 8 + xcd;       // 0..159
  int mm = r & 3;
  int ty = (g >> 3) * 4 + mm;       // 0..79
  if (ty >= *ntiles) return;
  int n0 = (g & 7) * 128;
  int e = tile_e[ty], m0 = tile_m0[ty];
  int base_slot = offsets[e] + m0;
  int cnt = counts[e] - m0; if (cnt > 128) cnt = 128;

  __shared__ unsigned short As[2][128 * 32];
  __shared__ unsigned short Bs[2][128 * 32];

  int t = threadIdx.x;
  int arow = t >> 2, kc = (t & 3) * 8;
  int r0i = base_slot + arow;      if (r0i > NSLOT - 1) r0i = NSLOT - 1;
  int r1i = base_slot + 64 + arow; if (r1i > NSLOT - 1) r1i = NSLOT - 1;
  const unsigned short* ag0 = H + (size_t)r0i * IDIM + kc;
  const unsigned short* ag1 = H + (size_t)r1i * IDIM + kc;
  int d0 = t * 8, d1 = 2048 + t * 8;

  int kk = t >> 5, nq = t & 31;
  const float* w2t = W2 + (size_t)e * IDIM * DDIM + (size_t)(kk * 4) * DDIM + (n0 + nq * 4);

  int lane = t & 63, wv = t >> 6;
  int wm = (wv >> 1) * 64, wn = (wv & 1) * 64;
  int lm = lane & 15, kg = lane >> 4;
  int ao[4], bo[4];
#pragma unroll
  for (int i = 0; i < 4; ++i) {
    ao[i] = (wm + i * 16 + lm) * 32 + kg * 8;
    int brow = wn + i * 16 + lm;
    bo[i] = brow * 64 + ((kg ^ ((brow >> 2) & 3)) << 4);
  }

  f32x4 acc[4][4];
#pragma unroll
  for (int i = 0; i < 4; ++i)
#pragma unroll
    for (int j = 0; j < 4; ++j) acc[i][j] = 0.f;

  {  // prologue
    gload_lds16(ag0, As[0] + d0);
    gload_lds16(ag1, As[0] + d1);
    f32x4 br[4];
    load_b(w2t, DDIM, true, br);
    write_b(br, Bs[0], kk, nq);
  }

  for (int k0 = 0; k0 < IDIM; k0 += 32) {
    int cur = (k0 >> 5) & 1, nx = cur ^ 1;
    __syncthreads();
    f32x4 br[4];
    bool more = (k0 + 32) < IDIM;
    if (more) {
      int kn = k0 + 32;
      gload_lds16(ag0 + kn, As[nx] + d0);
      gload_lds16(ag1 + kn, As[nx] + d1);
      load_b(w2t + (size_t)kn * DDIM, DDIM, true, br);
    }
    bf16x8 av[4], bv[4];
#pragma unroll
    for (int i = 0; i < 4; ++i) {
      av[i] = *(const bf16x8*)(As[cur] + ao[i]);
      bv[i] = *(const bf16x8*)((const char*)Bs[cur] + bo[i]);
    }
#pragma unroll
    for (int mi = 0; mi < 4; ++mi)
#pragma unroll
      for (int ni = 0; ni < 4; ++ni)
        acc[mi][ni] = __builtin_amdgcn_mfma_f32_16x16x32_bf16(av[mi], bv[ni], acc[mi][ni], 0, 0, 0);
    if (more) write_b(br, Bs[nx], kk, nq);
  }

#pragma unroll
  for (int mi = 0; mi < 4; ++mi)
#pragma unroll
    for (int rr = 0; rr < 4; ++rr) {
      int orow = wm + mi * 16 + kg * 4 + rr;
      if (orow < cnt) {
        unsigned short* op = O2 + (size_t)(base_slot + orow) * DDIM + n0;
#pragma unroll
        for (int ni = 0; ni < 4; ++ni)
          op[wn + ni * 16 + lm] = f2bf(acc[mi][ni][rr]);
      }
    }
}

// ---------------- combine: out[t] = O2[slot0] + O2[slot1] (bf16 in, fp32 out) ----------------
__global__ void k_combine(const unsigned short* __restrict__ O2, const int* __restrict__ slot_of,
                          float* __restrict__ out) {
  int tk = blockIdx.x, tt = threadIdx.x;
  int s0 = slot_of[2 * tk], s1 = slot_of[2 * tk + 1];
  us4 a = ((const us4*)(O2 + (size_t)s0 * DDIM))[tt];
  us4 b = ((const us4*)(O2 + (size_t)s1 * DDIM))[tt];
  f32x4 o;
#pragma unroll
  for (int j = 0; j < 4; ++j) o[j] = bf2f(a[j]) + bf2f(b[j]);
  ((f32x4*)(out + (size_t)tk * DDIM))[tt] = o;
}

extern "C" void kernel_launch(void* const* d_in, const int* in_sizes, int n_in,
                              void* d_out, int out_size, void* d_ws, size_t ws_size,
                              hipStream_t stream) {
  const float* x  = (const float*)d_in[0];
  const float* Wg = (const float*)d_in[1];
  const float* W1 = (const float*)d_in[2];
  const float* W2 = (const float*)d_in[3];   // dict order: x, Wg, W1, W2, W3
  const float* W3 = (const float*)d_in[4];
  float* out = (float*)d_out;

  char* ws = (char*)d_ws;
  size_t off = 0;
  unsigned short* Xb = (unsigned short*)(ws + off); off += (size_t)NTOK * DDIM * 2;
  unsigned short* H  = (unsigned short*)(ws + off); off += (size_t)NSLOT * IDIM * 2;
  unsigned short* O2 = (unsigned short*)(ws + off); off += (size_t)NSLOT * DDIM * 2;
  int* counts  = (int*)(ws + off); off += 64;
  int* offsets = (int*)(ws + off); off += 128;
  int* ntiles  = (int*)(ws + off); off += 64;
  int* tile_e  = (int*)(ws + off); off += MAXT * 4;
  int* tile_m0 = (int*)(ws + off); off += MAXT * 4;
  int* tok_e   = (int*)(ws + off); off += NSLOT * 4;
  float* tok_w = (float*)(ws + off); off += NSLOT * 4;
  int* token_map = (int*)(ws + off); off += NSLOT * 4;
  float* gate_w  = (float*)(ws + off); off += NSLOT * 4;
  int* slot_of   = (int*)(ws + off); off += NSLOT * 4;

  k_front<<<RTRBLK, 256, 0, stream>>>(x, Wg, tok_e, tok_w, Xb);
  k_scan_scatter<<<NEXP, 256, 0, stream>>>(tok_e, tok_w, counts, offsets, ntiles,
                                           tile_e, tile_m0, token_map, gate_w, slot_of);
  k_gemm1<<<480, 256, 0, stream>>>(Xb, W1, W3, token_map, gate_w, ntiles, tile_e,
                                   tile_m0, offsets, counts, H);
  k_gemm2<<<640, 256, 0, stream>>>(H, W2, ntiles, tile_e, tile_m0, offsets, counts, O2);
  k_combine<<<4096, 256, 0, stream>>>(O2, slot_of, out);
}